// Round 1
// 272.491 us; speedup vs baseline: 1.0295x; 1.0295x over previous
//
#include <hip/hip_runtime.h>
#include <math.h>

// C=64 channels, D_POS=3, B=64 x N_PER=8192, k = 4096.
#define C 64
#define DPOS 3
#define NPER 8192
#define KK 4096

typedef unsigned long long ull;

// Key: high 32 bits = order-inverted f32 score bits (ascending key <=> descending
// score), low 32 bits = in-batch index (ties -> lower index, = jax.lax.top_k).
__device__ __forceinline__ ull make_key(float s, unsigned idx) {
    unsigned u = __float_as_uint(s);
    unsigned o = (u >> 31) ? ~u : (u | 0x80000000u);
    unsigned d = ~o;
    return ((ull)d << 32) | (ull)idx;
}
__device__ __forceinline__ float key_score(ull key) {
    unsigned o = ~(unsigned)(key >> 32);
    unsigned u = (o >> 31) ? (o & 0x7FFFFFFFu) : ~o;
    return __uint_as_float(u);
}

// K1: fused score + 2048-chunk bitonic sort.
// Score phase: 16 lanes/row (one float4 each), 64 rows/WG/iter, fully coalesced.
// FP op order identical to the previous standalone score kernel -> bit-identical
// keys -> identical selection. Keys go straight to LDS (no HBM round-trip),
// then the proven 2048-key bitonic runs and writes sorted runs.
#define CH 2048
#define CTH 1024
__global__ __launch_bounds__(CTH) void score_sort(const float* __restrict__ weights,
                                                  const float* __restrict__ w,
                                                  ull* __restrict__ keys) {
    __shared__ ull lds[CH];
    const int tid = threadIdx.x;
    const float4* wv4 = (const float4*)w;
    float nrm = 0.f;
    #pragma unroll
    for (int i = 0; i < 16; ++i) {
        float4 t = wv4[i];
        nrm += t.x * t.x + t.y * t.y + t.z * t.z + t.w * t.w;
    }
    float nw = sqrtf(nrm);
    const int r16 = tid >> 4;   // 0..63: row within the 64-row stripe
    const int c4  = tid & 15;   // float4 column
    float4 wv = wv4[c4];
    const size_t base = (size_t)blockIdx.x * CH;
    #pragma unroll 4
    for (int it = 0; it < CH / 64; ++it) {
        int rl = it * 64 + r16;
        float4 x = ((const float4*)weights)[(base + rl) * 16 + c4];
        float acc = x.x * wv.x + x.y * wv.y + x.z * wv.z + x.w * wv.w;
        #pragma unroll
        for (int off = 8; off >= 1; off >>= 1) acc += __shfl_xor(acc, off, 16);
        if (c4 == 0)
            lds[rl] = make_key(tanhf(acc / nw), (unsigned)((base + rl) & (NPER - 1)));
    }
    // first pass of the sort loop begins with __syncthreads -> score writes visible
    for (unsigned k = 2; k <= CH; k <<= 1) {
        for (unsigned j = k >> 1; j > 0; j >>= 1) {
            __syncthreads();
            #pragma unroll
            for (int s = 0; s < CH / CTH; ++s) {
                unsigned i = tid + s * CTH;
                unsigned ixj = i ^ j;
                if (ixj > i) {
                    ull a = lds[i], b = lds[ixj];
                    bool up = ((i & k) == 0);
                    if ((a > b) == up) { lds[i] = b; lds[ixj] = a; }
                }
            }
        }
    }
    __syncthreads();
    #pragma unroll
    for (int s = 0; s < CH / CTH; ++s) keys[base + tid + s * CTH] = lds[tid + s * CTH];
}

// K2: both merge levels of one batch entirely in LDS (one WG per batch).
// Level 1: merge the two 2048-run pairs -> two 4096 runs, register-staged,
// in-place writeback separated by barriers. Level 2: merge 4096+4096 but emit
// only the first (top) 4096 keys straight to global. All binary searches hit
// LDS (~120 cy) instead of the old merge_tiled serial GLOBAL probes (~900 cy).
// Keys are unique (idx in low bits) so the comparator is a strict total order.
__global__ __launch_bounds__(1024) void merge_batch(const ull* __restrict__ src,
                                                    ull* __restrict__ dst) {
    __shared__ ull ld[NPER];   // 64 KB
    const int tid = threadIdx.x;
    const ull* bk = src + (size_t)blockIdx.x * NPER;
    #pragma unroll
    for (int s = 0; s < NPER / 1024; ++s) ld[tid + s * 1024] = bk[tid + s * 1024];
    __syncthreads();
    // ---- Level 1: pairs (0,1)->[0:4096), (2,3)->[4096:8192), 8 outputs/thread
    ull r[8];
    {
        int p = tid >> 9;              // pair id: 512 threads per pair
        int o = (tid & 511) * 8;       // output offset within pair
        const ull* A = ld + p * 4096;
        const ull* B = A + 2048;
        int lo = o - 2048; if (lo < 0) lo = 0;
        int hi = o < 2048 ? o : 2048;
        while (lo < hi) {
            int m = (lo + hi) >> 1;
            if (A[m] < B[o - 1 - m]) lo = m + 1; else hi = m;
        }
        int a = lo, b = o - lo;
        #pragma unroll
        for (int t = 0; t < 8; ++t) {
            bool fromA = (b >= 2048) || (a < 2048 && A[a] < B[b]);
            r[t] = fromA ? A[a++] : B[b++];
        }
        __syncthreads();               // all reads done before any writeback
        #pragma unroll
        for (int t = 0; t < 8; ++t) ld[p * 4096 + o + t] = r[t];
        __syncthreads();
    }
    // ---- Level 2: top-4096 of [0:4096)+[4096:8192), 4 outputs/thread -> global
    {
        int o = tid * 4;
        const ull* A = ld;
        const ull* B = ld + 4096;
        int lo = o - 4096; if (lo < 0) lo = 0;
        int hi = o < 4096 ? o : 4096;
        while (lo < hi) {
            int m = (lo + hi) >> 1;
            if (A[m] < B[o - 1 - m]) lo = m + 1; else hi = m;
        }
        int a = lo, b = o - lo;
        ull* D = dst + (size_t)blockIdx.x * KK + o;
        #pragma unroll
        for (int t = 0; t < 4; ++t) {
            bool fromA = (b >= 4096) || (a < 4096 && A[a] < B[b]);
            D[t] = fromA ? A[a++] : B[b++];
        }
    }
}

// Fallback (ws too small): monolithic per-batch bitonic (proven in R0).
// Input may be the sorted 2048-runs from score_sort; bitonic sorts any input.
__global__ __launch_bounds__(1024) void sort_full(ull* __restrict__ keys) {
    __shared__ ull lds[NPER];
    const unsigned tid = threadIdx.x;
    ull* bk = keys + (size_t)blockIdx.x * NPER;
    #pragma unroll
    for (int s = 0; s < NPER / 1024; ++s) lds[tid + s * 1024] = bk[tid + s * 1024];
    for (unsigned k = 2; k <= NPER; k <<= 1) {
        for (unsigned j = k >> 1; j > 0; j >>= 1) {
            __syncthreads();
            #pragma unroll
            for (int s = 0; s < NPER / 1024; ++s) {
                unsigned i = tid + s * 1024;
                unsigned ixj = i ^ j;
                if (ixj > i) {
                    ull a = lds[i], b = lds[ixj];
                    bool up = ((i & k) == 0);
                    if ((a > b) == up) { lds[i] = b; lds[ixj] = a; }
                }
            }
        }
    }
    __syncthreads();
    #pragma unroll
    for (int s = 0; s < NPER / 1024; ++s) bk[tid + s * 1024] = lds[tid + s * 1024];
}

// Gather: 16 lanes/row (float4 each), 4 rows/wave, 1 KB coalesced stores.
__global__ __launch_bounds__(256) void gather_kernel(const float* __restrict__ positions,
                                                     const float* __restrict__ weights,
                                                     const ull* __restrict__ keys,
                                                     float* __restrict__ out_pos,
                                                     float* __restrict__ out_w,
                                                     float* __restrict__ out_batch,
                                                     int rows, int nb, int kstr) {
    int gid = blockIdx.x * blockDim.x + threadIdx.x;
    if (gid < nb) out_batch[gid] = (float)KK;
    int lane = gid & 63;
    int sub = lane >> 4, c4 = lane & 15;
    int r = (gid >> 6) * 4 + sub;
    if (r >= rows) return;
    int b = r >> 12;           // / KK
    int j = r & (KK - 1);
    ull key = keys[(size_t)b * kstr + j];
    unsigned idx = (unsigned)key;
    size_t node = ((size_t)b << 13) + idx;
    float s = key_score(key);
    float4 x = ((const float4*)weights)[node * 16 + c4];
    float4 y; y.x = x.x * s; y.y = x.y * s; y.z = x.z * s; y.w = x.w * s;
    ((float4*)out_w)[(size_t)r * 16 + c4] = y;
    if (c4 < DPOS)
        out_pos[(size_t)r * DPOS + c4] = positions[node * DPOS + c4];
}

extern "C" void kernel_launch(void* const* d_in, const int* in_sizes, int n_in,
                              void* d_out, int out_size, void* d_ws, size_t ws_size,
                              hipStream_t stream) {
    const float* positions = (const float*)d_in[0];
    const float* weights   = (const float*)d_in[1];
    const float* w         = (const float*)d_in[2];

    int n  = in_sizes[1] / C;   // 524288
    int nb = in_sizes[3];       // 64
    int rows = nb * KK;         // 262144

    ull* bufA = (ull*)d_ws;
    ull* bufB = bufA + n;
    bool have_dbuf = ws_size >= ((size_t)n + (size_t)rows) * sizeof(ull);

    // Fused score + chunk sort: sorted 2048-runs into bufA (no keys round-trip).
    score_sort<<<n / CH, CTH, 0, stream>>>(weights, w, bufA);

    const ull* sorted_keys;
    int kstr;
    if (have_dbuf) {
        // Both merge levels in LDS, one WG per batch; emits top-4096 per batch.
        merge_batch<<<nb, 1024, 0, stream>>>(bufA, bufB);
        sorted_keys = bufB; kstr = KK;
    } else {
        sort_full<<<nb, 1024, 0, stream>>>(bufA);
        sorted_keys = bufA; kstr = NPER;
    }

    long long gthreads = (long long)(rows / 4) * 64;
    gather_kernel<<<(int)((gthreads + 255) / 256), 256, 0, stream>>>(
        positions, weights, sorted_keys, (float*)d_out,
        (float*)d_out + (size_t)rows * DPOS,
        (float*)d_out + (size_t)rows * (DPOS + C),
        rows, nb, kstr);
}

// Round 2
// 268.707 us; speedup vs baseline: 1.0440x; 1.0141x over previous
//
#include <hip/hip_runtime.h>
#include <math.h>

// C=64 channels, D_POS=3, B=64 x N_PER=8192, k = 4096.
#define C 64
#define DPOS 3
#define NPER 8192
#define KK 4096

typedef unsigned long long ull;

// Key: high 32 bits = order-inverted f32 score bits (ascending key <=> descending
// score), low 32 bits = in-batch index (ties -> lower index, = jax.lax.top_k).
__device__ __forceinline__ ull make_key(float s, unsigned idx) {
    unsigned u = __float_as_uint(s);
    unsigned o = (u >> 31) ? ~u : (u | 0x80000000u);
    unsigned d = ~o;
    return ((ull)d << 32) | (ull)idx;
}
__device__ __forceinline__ float key_score(ull key) {
    unsigned o = ~(unsigned)(key >> 32);
    unsigned u = (o >> 31) ? (o & 0x7FFFFFFFu) : ~o;
    return __uint_as_float(u);
}

// K1: fused score + 512-chunk bitonic sort.
// CH=512/CTH=256 (R2 change): 1024 WGs x 4 waves -> 4 WGs/CU, 16 waves/CU.
// vs the old CH=2048/CTH=1024 (1 WG/CU, 16-wave barriers): 45 passes instead of
// 66, 4-wave barriers, and 4 independent WGs/CU hide LDS latency during each
// other's barrier stalls -> sort phase goes latency-bound -> throughput-bound.
// Score FP op order identical to proven kernel -> bit-identical keys.
#define CH 512
#define CTH 256
__global__ __launch_bounds__(CTH) void score_sort(const float* __restrict__ weights,
                                                  const float* __restrict__ w,
                                                  ull* __restrict__ keys) {
    __shared__ ull lds[CH];
    const int tid = threadIdx.x;
    const float4* wv4 = (const float4*)w;
    float nrm = 0.f;
    #pragma unroll
    for (int i = 0; i < 16; ++i) {
        float4 t = wv4[i];
        nrm += t.x * t.x + t.y * t.y + t.z * t.z + t.w * t.w;
    }
    float nw = sqrtf(nrm);
    const int r16 = tid >> 4;   // 0..15: row within the 16-row stripe
    const int c4  = tid & 15;   // float4 column
    float4 wv = wv4[c4];
    const size_t base = (size_t)blockIdx.x * CH;
    #pragma unroll 4
    for (int it = 0; it < CH / 16; ++it) {
        int rl = it * 16 + r16;
        float4 x = ((const float4*)weights)[(base + rl) * 16 + c4];
        float acc = x.x * wv.x + x.y * wv.y + x.z * wv.z + x.w * wv.w;
        #pragma unroll
        for (int off = 8; off >= 1; off >>= 1) acc += __shfl_xor(acc, off, 16);
        if (c4 == 0)
            lds[rl] = make_key(tanhf(acc / nw), (unsigned)((base + rl) & (NPER - 1)));
    }
    // first pass of the sort loop begins with __syncthreads -> score writes visible
    for (unsigned k = 2; k <= CH; k <<= 1) {
        for (unsigned j = k >> 1; j > 0; j >>= 1) {
            __syncthreads();
            #pragma unroll
            for (int s = 0; s < CH / CTH; ++s) {
                unsigned i = tid + s * CTH;
                unsigned ixj = i ^ j;
                if (ixj > i) {
                    ull a = lds[i], b = lds[ixj];
                    bool up = ((i & k) == 0);
                    if ((a > b) == up) { lds[i] = b; lds[ixj] = a; }
                }
            }
        }
    }
    __syncthreads();
    #pragma unroll
    for (int s = 0; s < CH / CTH; ++s) keys[base + tid + s * CTH] = lds[tid + s * CTH];
}

// K2: all merge levels of one batch entirely in LDS (one WG per batch).
// Input: 16 sorted runs of 512. Levels L=512,1024,2048 merge pairs in place
// (register-staged, barrier-separated); final level emits only the top 4096
// straight to global. All binary searches hit LDS. Keys unique -> total order.
__global__ __launch_bounds__(1024) void merge_batch(const ull* __restrict__ src,
                                                    ull* __restrict__ dst) {
    __shared__ ull ld[NPER];   // 64 KB
    const int tid = threadIdx.x;
    const ull* bk = src + (size_t)blockIdx.x * NPER;
    #pragma unroll
    for (int s = 0; s < NPER / 1024; ++s) ld[tid + s * 1024] = bk[tid + s * 1024];
    __syncthreads();
    // ---- Full levels: pairs of runs length L -> runs length 2L, 8 outputs/thread
    #pragma unroll
    for (int lv = 0; lv < 3; ++lv) {
        const int L = 512 << lv;
        const int tpp = L / 4;            // threads per pair (128,256,512)
        int p = tid / tpp;
        int o = (tid - p * tpp) * 8;      // output offset within pair
        ull* A = ld + p * 2 * L;
        ull* B = A + L;
        int lo = o - L; if (lo < 0) lo = 0;
        int hi = o < L ? o : L;
        while (lo < hi) {
            int m = (lo + hi) >> 1;
            if (A[m] < B[o - 1 - m]) lo = m + 1; else hi = m;
        }
        int a = lo, b = o - lo;
        ull r[8];
        #pragma unroll
        for (int t = 0; t < 8; ++t) {
            bool fromA = (b >= L) || (a < L && A[a] < B[b]);
            r[t] = fromA ? A[a++] : B[b++];
        }
        __syncthreads();                  // all reads done before any writeback
        #pragma unroll
        for (int t = 0; t < 8; ++t) A[o + t] = r[t];
        __syncthreads();
    }
    // ---- Final: top-4096 of [0:4096)+[4096:8192), 4 outputs/thread -> global
    {
        int o = tid * 4;
        const ull* A = ld;
        const ull* B = ld + 4096;
        int lo = o - 4096; if (lo < 0) lo = 0;
        int hi = o < 4096 ? o : 4096;
        while (lo < hi) {
            int m = (lo + hi) >> 1;
            if (A[m] < B[o - 1 - m]) lo = m + 1; else hi = m;
        }
        int a = lo, b = o - lo;
        ull* D = dst + (size_t)blockIdx.x * KK + o;
        #pragma unroll
        for (int t = 0; t < 4; ++t) {
            bool fromA = (b >= 4096) || (a < 4096 && A[a] < B[b]);
            D[t] = fromA ? A[a++] : B[b++];
        }
    }
}

// Fallback (ws too small): monolithic per-batch bitonic (proven in R0).
// Input may be the sorted 512-runs from score_sort; bitonic sorts any input.
__global__ __launch_bounds__(1024) void sort_full(ull* __restrict__ keys) {
    __shared__ ull lds[NPER];
    const unsigned tid = threadIdx.x;
    ull* bk = keys + (size_t)blockIdx.x * NPER;
    #pragma unroll
    for (int s = 0; s < NPER / 1024; ++s) lds[tid + s * 1024] = bk[tid + s * 1024];
    for (unsigned k = 2; k <= NPER; k <<= 1) {
        for (unsigned j = k >> 1; j > 0; j >>= 1) {
            __syncthreads();
            #pragma unroll
            for (int s = 0; s < NPER / 1024; ++s) {
                unsigned i = tid + s * 1024;
                unsigned ixj = i ^ j;
                if (ixj > i) {
                    ull a = lds[i], b = lds[ixj];
                    bool up = ((i & k) == 0);
                    if ((a > b) == up) { lds[i] = b; lds[ixj] = a; }
                }
            }
        }
    }
    __syncthreads();
    #pragma unroll
    for (int s = 0; s < NPER / 1024; ++s) bk[tid + s * 1024] = lds[tid + s * 1024];
}

// Gather: 16 lanes/row (float4 each), 4 rows/wave, 1 KB coalesced stores.
__global__ __launch_bounds__(256) void gather_kernel(const float* __restrict__ positions,
                                                     const float* __restrict__ weights,
                                                     const ull* __restrict__ keys,
                                                     float* __restrict__ out_pos,
                                                     float* __restrict__ out_w,
                                                     float* __restrict__ out_batch,
                                                     int rows, int nb, int kstr) {
    int gid = blockIdx.x * blockDim.x + threadIdx.x;
    if (gid < nb) out_batch[gid] = (float)KK;
    int lane = gid & 63;
    int sub = lane >> 4, c4 = lane & 15;
    int r = (gid >> 6) * 4 + sub;
    if (r >= rows) return;
    int b = r >> 12;           // / KK
    int j = r & (KK - 1);
    ull key = keys[(size_t)b * kstr + j];
    unsigned idx = (unsigned)key;
    size_t node = ((size_t)b << 13) + idx;
    float s = key_score(key);
    float4 x = ((const float4*)weights)[node * 16 + c4];
    float4 y; y.x = x.x * s; y.y = x.y * s; y.z = x.z * s; y.w = x.w * s;
    ((float4*)out_w)[(size_t)r * 16 + c4] = y;
    if (c4 < DPOS)
        out_pos[(size_t)r * DPOS + c4] = positions[node * DPOS + c4];
}

extern "C" void kernel_launch(void* const* d_in, const int* in_sizes, int n_in,
                              void* d_out, int out_size, void* d_ws, size_t ws_size,
                              hipStream_t stream) {
    const float* positions = (const float*)d_in[0];
    const float* weights   = (const float*)d_in[1];
    const float* w         = (const float*)d_in[2];

    int n  = in_sizes[1] / C;   // 524288
    int nb = in_sizes[3];       // 64
    int rows = nb * KK;         // 262144

    ull* bufA = (ull*)d_ws;
    ull* bufB = bufA + n;
    bool have_dbuf = ws_size >= ((size_t)n + (size_t)rows) * sizeof(ull);

    // Fused score + chunk sort: sorted 512-runs into bufA (no keys round-trip).
    score_sort<<<n / CH, CTH, 0, stream>>>(weights, w, bufA);

    const ull* sorted_keys;
    int kstr;
    if (have_dbuf) {
        // All merge levels in LDS, one WG per batch; emits top-4096 per batch.
        merge_batch<<<nb, 1024, 0, stream>>>(bufA, bufB);
        sorted_keys = bufB; kstr = KK;
    } else {
        sort_full<<<nb, 1024, 0, stream>>>(bufA);
        sorted_keys = bufA; kstr = NPER;
    }

    long long gthreads = (long long)(rows / 4) * 64;
    gather_kernel<<<(int)((gthreads + 255) / 256), 256, 0, stream>>>(
        positions, weights, sorted_keys, (float*)d_out,
        (float*)d_out + (size_t)rows * DPOS,
        (float*)d_out + (size_t)rows * (DPOS + C),
        rows, nb, kstr);
}